// Round 3
// baseline (1102.323 us; speedup 1.0000x reference)
//
#include <hip/hip_runtime.h>

#define DD   172
#define TK   516      // 3*D
#define BB   500
#define KK   10
#define MM   1000
#define MSGW 688
#define NR1  1500     // 3*B
#define NR2  15000    // 3*B*K

__device__ __forceinline__ float sigm(float x){ return 1.f / (1.f + expf(-x)); }

// ---------------- GRU memory update, 8 msgs/block (in-place) --------------
// msg_node_ids = arange(1000): each block touches only its own rows.
__global__ void k_gru(const float* __restrict__ msgs, float* memory,
                      const float* __restrict__ W_ih, const float* __restrict__ W_hh,
                      const float* __restrict__ b_ih, const float* __restrict__ b_hh,
                      const int* __restrict__ ids){
  int t = threadIdx.x;
  int r0 = blockIdx.x * 8;               // 125*8 = 1000 exact
  __shared__ float x[8][MSGW];
  __shared__ float h[8][DD];
  __shared__ int   sid[8];
  if (t < 8) sid[t] = ids[r0 + t];
  for (int rr = 0; rr < 8; rr++)
    for (int c = t; c < MSGW; c += 192)
      x[rr][c] = msgs[(size_t)(r0 + rr)*MSGW + c];
  __syncthreads();
  if (t < DD)
    for (int rr = 0; rr < 8; rr++)
      h[rr][t] = memory[(size_t)sid[rr]*DD + t];
  __syncthreads();
  if (t < DD){
    float gi0[8], gi1[8], gi2[8];
    float bi0 = b_ih[t], bi1 = b_ih[DD+t], bi2 = b_ih[2*DD+t];
    #pragma unroll
    for (int rr = 0; rr < 8; rr++){ gi0[rr]=bi0; gi1[rr]=bi1; gi2[rr]=bi2; }
    const float* w0 = W_ih + (size_t)t*MSGW;
    const float* w1 = W_ih + (size_t)(DD+t)*MSGW;
    const float* w2 = W_ih + (size_t)(2*DD+t)*MSGW;
    for (int c = 0; c < MSGW; c++){
      float a0 = w0[c], a1 = w1[c], a2 = w2[c];
      #pragma unroll
      for (int rr = 0; rr < 8; rr++){
        float xv = x[rr][c];
        gi0[rr] = fmaf(xv, a0, gi0[rr]);
        gi1[rr] = fmaf(xv, a1, gi1[rr]);
        gi2[rr] = fmaf(xv, a2, gi2[rr]);
      }
    }
    float gh0[8], gh1[8], gh2[8];
    float bh0 = b_hh[t], bh1 = b_hh[DD+t], bh2 = b_hh[2*DD+t];
    #pragma unroll
    for (int rr = 0; rr < 8; rr++){ gh0[rr]=bh0; gh1[rr]=bh1; gh2[rr]=bh2; }
    const float* v0 = W_hh + (size_t)t*DD;
    const float* v1 = W_hh + (size_t)(DD+t)*DD;
    const float* v2 = W_hh + (size_t)(2*DD+t)*DD;
    for (int c = 0; c < DD; c++){
      float a0 = v0[c], a1 = v1[c], a2 = v2[c];
      #pragma unroll
      for (int rr = 0; rr < 8; rr++){
        float hv = h[rr][c];
        gh0[rr] = fmaf(hv, a0, gh0[rr]);
        gh1[rr] = fmaf(hv, a1, gh1[rr]);
        gh2[rr] = fmaf(hv, a2, gh2[rr]);
      }
    }
    #pragma unroll
    for (int rr = 0; rr < 8; rr++){
      float r = sigm(gi0[rr] + gh0[rr]);
      float z = sigm(gi1[rr] + gh1[rr]);
      float g = tanhf(gi2[rr] + r*gh2[rr]);
      float hn = (1.f - z)*g + z*h[rr][t];
      memory[(size_t)sid[rr]*DD + t] = hn;
    }
  }
}

// ---------------- lin2 "st" constant: c2_l[j] = b2_l[j] + sum_d cos(b_d) W2_l[2D+d][j]
// consts layout: [0:172) c2_0, [172:344) c2_1
__global__ void k_c2(const float* __restrict__ time_b, const float* __restrict__ lin2_w,
                     const float* __restrict__ lin2_b, float* __restrict__ consts){
  int l = blockIdx.x, j = threadIdx.x;
  __shared__ float cb[DD];
  if (j < DD) cb[j] = cosf(time_b[j]);
  __syncthreads();
  if (j < DD){
    float acc = lin2_b[(size_t)l*DD + j];
    const float* W = lin2_w + (size_t)l*TK*DD;
    for (int d = 0; d < DD; d++) acc = fmaf(cb[d], W[(size_t)(2*DD + d)*DD + j], acc);
    consts[l*DD + j] = acc;
  }
}

// ---------------- hop-2 fused: nbr sums -> lin1 -> [h|src] -> lin2 -> emb1
__global__ void k_hop2(const float* __restrict__ nf, const float* __restrict__ ef,
                       const float* __restrict__ mem, const float* __restrict__ tw,
                       const float* __restrict__ tb, const float* __restrict__ et,
                       const float* __restrict__ n2t, const int* __restrict__ n2i,
                       const int* __restrict__ n2e, const int* __restrict__ n1i,
                       const float* __restrict__ l1w, const float* __restrict__ l2w,
                       const float* __restrict__ l1b, const float* __restrict__ consts,
                       float* __restrict__ emb1){
  int t = threadIdx.x;
  int r0 = blockIdx.x * 8;                 // 1875*8 = 15000 exact
  __shared__ float S[8][TK];
  __shared__ float H[8][2*DD];
  if (t < DD){
    float w = tw[t], b = tb[t];
    for (int rr = 0; rr < 8; rr++){
      int r = r0 + rr;
      float ts = et[(r/KK) % BB];          // ts1 = repeat(concat(et,et,et), K)
      float sn = 0.f, sd = 0.f, se = 0.f;
      for (int k = 0; k < KK; k++){
        int id = n2i[(size_t)r*KK + k];
        int e  = n2e[(size_t)r*KK + k];
        float dt = ts - n2t[(size_t)r*KK + k];
        sn += mem[(size_t)id*DD + t] + nf[(size_t)id*DD + t];
        sd += cosf(dt*w + b);
        se += ef[(size_t)e*DD + t];
      }
      S[rr][t] = sn; S[rr][DD + t] = sd; S[rr][2*DD + t] = se;
      int sid = n1i[r];                    // src of hop-2 row = flat nbr1_ids
      H[rr][DD + t] = mem[(size_t)sid*DD + t] + nf[(size_t)sid*DD + t];
    }
  }
  __syncthreads();
  if (t < DD){                             // h = relu(S @ W1_0 + 10*b1_0)
    float acc[8];
    float b10 = 10.f * l1b[t];
    #pragma unroll
    for (int rr = 0; rr < 8; rr++) acc[rr] = b10;
    for (int c = 0; c < TK; c++){
      float wv = l1w[(size_t)c*DD + t];
      #pragma unroll
      for (int rr = 0; rr < 8; rr++) acc[rr] = fmaf(S[rr][c], wv, acc[rr]);
    }
    #pragma unroll
    for (int rr = 0; rr < 8; rr++) H[rr][t] = fmaxf(acc[rr], 0.f);
  }
  __syncthreads();
  if (t < DD){                             // emb1 = [h|src] @ W2_0[0:344] + c2_0
    float acc[8];
    float c2 = consts[t];
    #pragma unroll
    for (int rr = 0; rr < 8; rr++) acc[rr] = c2;
    for (int c = 0; c < 2*DD; c++){
      float wv = l2w[(size_t)c*DD + t];
      #pragma unroll
      for (int rr = 0; rr < 8; rr++) acc[rr] = fmaf(H[rr][c], wv, acc[rr]);
    }
    #pragma unroll
    for (int rr = 0; rr < 8; rr++) emb1[(size_t)(r0+rr)*DD + t] = acc[rr];
  }
}

// ---------------- hop-1 fused: layer-1 weights, emb2 f32 ------------------
__global__ void k_hop1(const float* __restrict__ nf, const float* __restrict__ ef,
                       const float* __restrict__ mem, const float* __restrict__ tw,
                       const float* __restrict__ tb, const float* __restrict__ et,
                       const float* __restrict__ n1t, const int* __restrict__ n1e,
                       const int* __restrict__ src, const int* __restrict__ dst,
                       const int* __restrict__ neg, const float* __restrict__ emb1,
                       const float* __restrict__ l1w, const float* __restrict__ l2w,
                       const float* __restrict__ l1b, const float* __restrict__ consts,
                       float* __restrict__ emb2){
  int t = threadIdx.x;
  int r0 = blockIdx.x * 8;                 // 188 blocks; clamp reads, guard writes
  __shared__ float S[8][TK];
  __shared__ float H[8][2*DD];
  if (t < DD){
    float w = tw[t], b = tb[t];
    for (int rr = 0; rr < 8; rr++){
      int q = r0 + rr; if (q >= NR1) q = NR1 - 1;
      float ts = et[q % BB];
      float sn = 0.f, sd = 0.f, se = 0.f;
      for (int k = 0; k < KK; k++){
        int e = n1e[(size_t)q*KK + k];
        float dt = ts - n1t[(size_t)q*KK + k];
        sn += emb1[((size_t)q*KK + k)*DD + t];
        sd += cosf(dt*w + b);
        se += ef[(size_t)e*DD + t];
      }
      S[rr][t] = sn; S[rr][DD + t] = sd; S[rr][2*DD + t] = se;
      int sid = (q < BB) ? src[q] : (q < 2*BB ? dst[q - BB] : neg[q - 2*BB]);
      H[rr][DD + t] = mem[(size_t)sid*DD + t] + nf[(size_t)sid*DD + t];
    }
  }
  __syncthreads();
  if (t < DD){
    float acc[8];
    float b10 = 10.f * l1b[t];
    #pragma unroll
    for (int rr = 0; rr < 8; rr++) acc[rr] = b10;
    for (int c = 0; c < TK; c++){
      float wv = l1w[(size_t)c*DD + t];
      #pragma unroll
      for (int rr = 0; rr < 8; rr++) acc[rr] = fmaf(S[rr][c], wv, acc[rr]);
    }
    #pragma unroll
    for (int rr = 0; rr < 8; rr++) H[rr][t] = fmaxf(acc[rr], 0.f);
  }
  __syncthreads();
  if (t < DD){
    float acc[8];
    float c2 = consts[DD + t];
    #pragma unroll
    for (int rr = 0; rr < 8; rr++) acc[rr] = c2;
    for (int c = 0; c < 2*DD; c++){
      float wv = l2w[(size_t)c*DD + t];
      #pragma unroll
      for (int rr = 0; rr < 8; rr++) acc[rr] = fmaf(H[rr][c], wv, acc[rr]);
    }
    #pragma unroll
    for (int rr = 0; rr < 8; rr++){
      int q = r0 + rr;
      if (q < NR1) emb2[(size_t)q*DD + t] = acc[rr];
    }
  }
}

// ---------------- affinity head -------------------------------------------
__global__ void k_merge(const float* __restrict__ emb2, const float* __restrict__ aff_w1,
                        const float* __restrict__ aff_b1, const float* __restrict__ aff_w2,
                        const float* __restrict__ aff_b2, float* __restrict__ out){
  int idx = blockIdx.x;            // 0..999: [0,500) pos, [500,1000) neg
  int which = idx / BB, r = idx % BB;
  int t = threadIdx.x;
  __shared__ float x1[DD], x2[DD], hs[DD];
  if (t < DD){
    x1[t] = emb2[(size_t)r*DD + t];
    x2[t] = emb2[(size_t)(which == 0 ? BB + r : 2*BB + r)*DD + t];
  }
  __syncthreads();
  if (t < DD){
    float acc = aff_b1[t];
    for (int c = 0; c < DD; c++) acc = fmaf(x1[c], aff_w1[(size_t)c*DD + t], acc);
    for (int c = 0; c < DD; c++) acc = fmaf(x2[c], aff_w1[(size_t)(DD + c)*DD + t], acc);
    hs[t] = fmaxf(acc, 0.f) * aff_w2[t];
  }
  __syncthreads();
  if (t == 0){
    float s = aff_b2[0];
    for (int i = 0; i < DD; i++) s += hs[i];
    out[which*BB + r] = sigm(s);
  }
}

// ---------------- decode: emb2[0:1000] @ dec_w + dec_b --------------------
__global__ void k_dec(const float* __restrict__ emb2, const float* __restrict__ dec_w,
                      const float* __restrict__ dec_b, float* __restrict__ out){
  int t = threadIdx.x;
  int r0 = blockIdx.x * 8;                 // 125*8 = 1000 exact
  if (t < DD){
    float acc[8];
    float bj = dec_b[t];
    #pragma unroll
    for (int rr = 0; rr < 8; rr++) acc[rr] = bj;
    for (int c = 0; c < DD; c++){
      float wv = dec_w[(size_t)c*DD + t];
      #pragma unroll
      for (int rr = 0; rr < 8; rr++)
        acc[rr] = fmaf(emb2[(size_t)(r0+rr)*DD + c], wv, acc[rr]);
    }
    #pragma unroll
    for (int rr = 0; rr < 8; rr++) out[(size_t)(r0+rr)*DD + t] = acc[rr];
  }
}

// ---------------- raw output: node_feats gather ---------------------------
__global__ void k_raw(const float* __restrict__ node_feats, const int* __restrict__ src,
                      const int* __restrict__ dst, float* __restrict__ out){
  int q = blockIdx.x, t = threadIdx.x;
  int id = (q < BB) ? src[q] : dst[q - BB];
  if (t < DD) out[(size_t)q*DD + t] = node_feats[(size_t)id*DD + t];
}

extern "C" void kernel_launch(void* const* d_in, const int* in_sizes, int n_in,
                              void* d_out, int out_size, void* d_ws, size_t ws_size,
                              hipStream_t stream){
  (void)in_sizes; (void)n_in; (void)out_size; (void)ws_size;
  const float* node_feats = (const float*)d_in[0];
  const float* edge_feats = (const float*)d_in[1];
  float*       memory     = (float*)d_in[2];      // updated in place (harness restores)
  const float* time_w     = (const float*)d_in[3];
  const float* time_b     = (const float*)d_in[4];
  const float* W_ih       = (const float*)d_in[5];
  const float* W_hh       = (const float*)d_in[6];
  const float* b_ih       = (const float*)d_in[7];
  const float* b_hh       = (const float*)d_in[8];
  const float* lin1_w     = (const float*)d_in[9];
  const float* lin1_b     = (const float*)d_in[10];
  const float* lin2_w     = (const float*)d_in[11];
  const float* lin2_b     = (const float*)d_in[12];
  const float* aff_w1     = (const float*)d_in[13];
  const float* aff_b1     = (const float*)d_in[14];
  const float* aff_w2     = (const float*)d_in[15];
  const float* aff_b2     = (const float*)d_in[16];
  const float* dec_w      = (const float*)d_in[17];
  const float* dec_b      = (const float*)d_in[18];
  const float* edge_times = (const float*)d_in[19];
  const float* nbr1_t     = (const float*)d_in[20];
  const float* nbr2_t     = (const float*)d_in[21];
  const float* msgs       = (const float*)d_in[22];
  const int* src        = (const int*)d_in[24];
  const int* dst        = (const int*)d_in[25];
  const int* neg        = (const int*)d_in[26];
  const int* nbr1_ids   = (const int*)d_in[28];
  const int* nbr1_eidx  = (const int*)d_in[29];
  const int* nbr2_ids   = (const int*)d_in[30];
  const int* nbr2_eidx  = (const int*)d_in[31];
  const int* msg_ids    = (const int*)d_in[32];
  float* out = (float*)d_out;

  // ws layout (~11.4 MB): consts at offset 0.
  float* consts = (float*)d_ws;                               // 344 floats
  float* emb1   = (float*)((char*)d_ws + 2048);               // 15000*172 f32
  float* emb2   = emb1 + (size_t)NR2*DD;                      // 1500*172 f32

  k_gru <<<MM/8, 192, 0, stream>>>(msgs, memory, W_ih, W_hh, b_ih, b_hh, msg_ids);
  k_c2  <<<2, 192, 0, stream>>>(time_b, lin2_w, lin2_b, consts);
  k_hop2<<<NR2/8, 192, 0, stream>>>(node_feats, edge_feats, memory, time_w, time_b,
                                    edge_times, nbr2_t, nbr2_ids, nbr2_eidx, nbr1_ids,
                                    lin1_w, lin2_w, lin1_b, consts, emb1);
  k_hop1<<<(NR1+7)/8, 192, 0, stream>>>(node_feats, edge_feats, memory, time_w, time_b,
                                        edge_times, nbr1_t, nbr1_eidx, src, dst, neg,
                                        emb1, lin1_w + (size_t)TK*DD, lin2_w + (size_t)TK*DD,
                                        lin1_b + DD, consts, emb2);
  k_merge<<<2*BB, 192, 0, stream>>>(emb2, aff_w1, aff_b1, aff_w2, aff_b2, out);
  k_dec <<<MM/8, 192, 0, stream>>>(emb2, dec_w, dec_b, out + 2*BB);
  k_raw <<<MM, 192, 0, stream>>>(node_feats, src, dst, out + 2*BB + (size_t)MM*DD);
}